// Round 6
// baseline (119.423 us; speedup 1.0000x reference)
//
#include <hip/hip_runtime.h>
#include <stdint.h>

#define BATCH 32
#define NH    32
#define KVH   8
#define QPK   4
#define DH    128
#define BS    128
#define NEG   (-1e30f)
#define SCALEF 0.08838834764831845f  // 1/sqrt(128)
#define MAXU  64
#define NSP   8          // token-split WGs per (seq, kv-head)
#define CHK   8          // tokens per wave per block
#define KVROW (KVH * DH)

#define GAS __attribute__((address_space(1)))
#define LAS __attribute__((address_space(3)))

// 4 coalesced V float4 loads (8 tokens) into register array VR.
#define LOAD_V(PB, VR) do {                                                     \
  const float* vb_ = value_cache + ((size_t)(PB) * BS + T0 + half) * KVROW      \
                   + g * DH + r32 * 4;                                          \
  _Pragma("unroll")                                                             \
  for (int tp = 0; tp < 4; ++tp)                                                \
    VR[tp] = *(const float4*)&vb_[(size_t)tp * 2 * KVROW];                      \
} while (0)

// Stage 8 tokens x 512B of K into per-wave LDS buf BUFI via global_load_lds.
// XOR swizzle: LDS(row t, granule p) holds global granule p^t.
#define STAGE_K(PB, BUFI) do {                                                  \
  const float* kbase_ = key_cache + ((size_t)(PB) * BS + T0) * KVROW + g * DH;  \
  float* dst_ = &Kbuf[w][BUFI][0];                                              \
  _Pragma("unroll")                                                             \
  for (int seg = 0; seg < 4; ++seg) {                                           \
    const int t_  = 2 * seg + half;                                             \
    const int sg_ = r32 ^ t_;                                                   \
    __builtin_amdgcn_global_load_lds(                                           \
        (const GAS void*)(kbase_ + (size_t)t_ * KVROW + sg_ * 4),               \
        (LAS void*)(dst_ + seg * 256), 16, 0, 0);                               \
  }                                                                             \
} while (0)

// QK + online softmax for the 8-token chunk in buf BUFI. Lane = (token r8,
// d-octant oc): reads LDS slot (oc*4+i)^r8 (conflict-free by construction).
#define COMPUTE(BUFI, ABV) do {                                                 \
  const float* kb_ = &Kbuf[w][BUFI][0];                                         \
  float a0_ = 0.f, a1_ = 0.f, a2_ = 0.f, a3_ = 0.f;                             \
  _Pragma("unroll")                                                             \
  for (int i = 0; i < 4; ++i) {                                                 \
    const int gi_  = oc * 4 + i;                                                \
    const int pos_ = gi_ ^ r8;                                                  \
    const float4 kv = *(const float4*)&kb_[r8 * DH + pos_ * 4];                 \
    const float4 q0 = *(const float4*)&q_lds[0 * DH + gi_ * 4];                 \
    const float4 q1 = *(const float4*)&q_lds[1 * DH + gi_ * 4];                 \
    const float4 q2 = *(const float4*)&q_lds[2 * DH + gi_ * 4];                 \
    const float4 q3 = *(const float4*)&q_lds[3 * DH + gi_ * 4];                 \
    a0_ += kv.x*q0.x + kv.y*q0.y + kv.z*q0.z + kv.w*q0.w;                       \
    a1_ += kv.x*q1.x + kv.y*q1.y + kv.z*q1.z + kv.w*q1.w;                       \
    a2_ += kv.x*q2.x + kv.y*q2.y + kv.z*q2.z + kv.w*q2.w;                       \
    a3_ += kv.x*q3.x + kv.y*q3.y + kv.z*q3.z + kv.w*q3.w;                       \
  }                                                                             \
  float accv_[QPK] = {a0_, a1_, a2_, a3_};                                      \
  const bool valid_ = (T0 + r8) < us_c;                                         \
  float pr_[QPK];                                                               \
  _Pragma("unroll")                                                             \
  for (int qh = 0; qh < QPK; ++qh) {                                            \
    float sc = accv_[qh];                                                       \
    sc += __shfl_xor(sc, 8);  sc += __shfl_xor(sc, 16); sc += __shfl_xor(sc, 32);\
    sc += (ABV) * slope[qh];                                                    \
    if (!valid_) sc = NEG;                                                      \
    float cm = fmaxf(sc, __shfl_xor(sc, 1));                                    \
    cm = fmaxf(cm, __shfl_xor(cm, 2)); cm = fmaxf(cm, __shfl_xor(cm, 4));       \
    const float mnew = fmaxf(m[qh], cm);                                        \
    const float rs = __expf(m[qh] - mnew);                                      \
    m[qh] = mnew;                                                               \
    pr_[qh] = valid_ ? __expf(sc - mnew) : 0.f;                                 \
    sacc[qh] = sacc[qh] * rs + ((lane < 8) ? pr_[qh] : 0.f);                    \
    O[qh][0] *= rs; O[qh][1] *= rs; O[qh][2] *= rs; O[qh][3] *= rs;             \
  }                                                                             \
  if (lane < 8)                                                                 \
    *(float4*)&p_lds[w][r8 * 4] = make_float4(pr_[0], pr_[1], pr_[2], pr_[3]);  \
} while (0)

#define AV(VR) do {                                                             \
  _Pragma("unroll")                                                             \
  for (int tp = 0; tp < 4; ++tp) {                                              \
    const float4 pv = *(const float4*)&p_lds[w][(2 * tp + half) * 4];           \
    const float4 vv = VR[tp];                                                   \
    O[0][0]+=pv.x*vv.x; O[0][1]+=pv.x*vv.y; O[0][2]+=pv.x*vv.z; O[0][3]+=pv.x*vv.w; \
    O[1][0]+=pv.y*vv.x; O[1][1]+=pv.y*vv.y; O[1][2]+=pv.y*vv.z; O[1][3]+=pv.y*vv.w; \
    O[2][0]+=pv.z*vv.x; O[2][1]+=pv.z*vv.y; O[2][2]+=pv.z*vv.z; O[2][3]+=pv.z*vv.w; \
    O[3][0]+=pv.w*vv.x; O[3][1]+=pv.w*vv.y; O[3][2]+=pv.w*vv.z; O[3][3]+=pv.w*vv.w; \
  }                                                                             \
} while (0)

// One block body: single vmcnt(0) (all operands issued a full body earlier),
// then issue next block's V+ab+K, then compute with zero memory waits.
#define BODY(VCUR, VNXT, BUFC, BUFN, CIDX) do {                                 \
  __builtin_amdgcn_sched_barrier(0);                                            \
  asm volatile("s_waitcnt vmcnt(0)" ::: "memory");                              \
  __builtin_amdgcn_sched_barrier(0);                                            \
  const bool hn_ = (CIDX) + 1 < nblk;                                           \
  int u_n = 0, pb_n = 0, us_n = 0; float ab_n = 0.f;                            \
  if (hn_) {                                                                    \
    u_n = ulist[(CIDX) + 1]; pb_n = pblds[(CIDX) + 1]; us_n = uslds[(CIDX) + 1];\
    LOAD_V(pb_n, VNXT);                                                         \
    ab_n = alibi_blocks[(size_t)u_n * BS + T0 + r8];                            \
    __builtin_amdgcn_sched_barrier(0);                                          \
    STAGE_K(pb_n, BUFN);                                                        \
    __builtin_amdgcn_sched_barrier(0);                                          \
  }                                                                             \
  COMPUTE(BUFC, ab_c);                                                          \
  AV(VCUR);                                                                     \
  u_c = u_n; pb_c = pb_n; us_c = us_n; ab_c = ab_n;                             \
} while (0)

__global__ __launch_bounds__(128, 4)
void pa_partial(const float* __restrict__ query,
                const float* __restrict__ key_cache,
                const float* __restrict__ value_cache,
                const float* __restrict__ alibi_blocks,
                const float* __restrict__ alibi_slopes,
                const int* __restrict__ block_list,
                const int* __restrict__ block_groups,
                const int* __restrict__ block_usage,
                float* __restrict__ Mp, float* __restrict__ Sp,
                float* __restrict__ Op, int U) {
  __shared__ __align__(16) float Kbuf[2][2][CHK * DH];  // 16 KiB: per-wave dbuf
  __shared__ __align__(16) float q_lds[QPK * DH];       // 2 KiB
  __shared__ __align__(16) float p_lds[2][CHK * QPK];   // 256 B
  __shared__ int ulist[MAXU], pblds[MAXU], uslds[MAXU];
  __shared__ int ucount;

  const int tid  = threadIdx.x;
  const int w    = tid >> 6;
  const int lane = tid & 63;
  const int r32  = lane & 31;   // V/stage: d-granule
  const int half = lane >> 5;   // V/stage: token parity
  const int r8   = lane & 7;    // QK: token within chunk
  const int oc   = lane >> 3;   // QK: d-octant
  const int bid  = blockIdx.x;
  const int b    = bid >> 6;    // / (KVH*NSP)
  const int g    = (bid >> 3) & 7;
  const int s    = bid & 7;
  const int T0   = s * 16 + w * CHK;   // this wave's token slice in each block

  // ---- gather this sequence's block entries (order-preserving) ----
  if (w == 0) {
    int cnt = 0;
    for (int base = 0; base < U; base += 64) {
      const int u = base + lane;
      const bool match = (u < U) && (block_groups[u] == b);
      const unsigned long long mk = __ballot(match);
      if (match) {
        const int pre = __popcll(mk & ((1ull << lane) - 1ull));
        if (cnt + pre < MAXU) ulist[cnt + pre] = u;
      }
      cnt += __popcll(mk);
    }
    if (cnt > MAXU) cnt = MAXU;
    if (lane == 0) ucount = cnt;
    for (int i = lane; i < cnt; i += 64) {
      const int u = ulist[i];
      pblds[i] = block_list[u];
      uslds[i] = block_usage[u];
    }
  }

  // ---- scaled query -> LDS ----
  {
    const float* qsrc = query + ((size_t)b * NH + g * QPK) * DH;
    for (int e = tid; e < QPK * DH; e += 128) q_lds[e] = qsrc[e] * SCALEF;
  }

  float slope[QPK];
#pragma unroll
  for (int qh = 0; qh < QPK; ++qh) slope[qh] = alibi_slopes[g * QPK + qh];

  __syncthreads();

  const int nblk = ucount;

  float m[QPK], sacc[QPK], O[QPK][4];
#pragma unroll
  for (int qh = 0; qh < QPK; ++qh) {
    m[qh] = NEG; sacc[qh] = 0.f;
#pragma unroll
    for (int k = 0; k < 4; ++k) O[qh][k] = 0.f;
  }

  float4 vA[4], vB[4];
  int u_c = 0, pb_c = 0, us_c = 0;
  float ab_c = 0.f;

  if (nblk > 0) {  // prologue: block 0's V + ab + K
    u_c = ulist[0]; pb_c = pblds[0]; us_c = uslds[0];
    LOAD_V(pb_c, vA);
    ab_c = alibi_blocks[(size_t)u_c * BS + T0 + r8];
    STAGE_K(pb_c, 0);
  }

  for (int c = 0; c < nblk; c += 2) {
    BODY(vA, vB, 0, 1, c);
    if (c + 1 < nblk) BODY(vB, vA, 1, 0, c + 1);
  }

  // ---- per-wave finalize into own (dead) Kbuf slice ----
  float* cO  = &Kbuf[w][0][0];   // [qh*DH + d]
  float* cMS = &Kbuf[w][1][0];   // [qh]=M, [4+qh]=S
#pragma unroll
  for (int qh = 0; qh < QPK; ++qh) {
    float sv = sacc[qh];
#pragma unroll
    for (int off = 1; off < 64; off <<= 1) sv += __shfl_xor(sv, off);
#pragma unroll
    for (int k = 0; k < 4; ++k) O[qh][k] += __shfl_xor(O[qh][k], 32);
    if (half == 0) {
#pragma unroll
      for (int k = 0; k < 4; ++k) cO[qh * DH + r32 * 4 + k] = O[qh][k];
    }
    if (lane == 0) { cMS[qh] = m[qh]; cMS[4 + qh] = sv; }
  }
  __syncthreads();

  // ---- cross-wave (2) flash combine -> partial (M,S,O) to workspace ----
  for (int e = tid; e < QPK * DH; e += 128) {
    const int qh = e >> 7, d = e & 127;
    const float M  = fmaxf(Kbuf[0][1][qh], Kbuf[1][1][qh]);
    const float f0 = __expf(Kbuf[0][1][qh] - M);
    const float f1 = __expf(Kbuf[1][1][qh] - M);
    const float S  = f0 * Kbuf[0][1][4 + qh] + f1 * Kbuf[1][1][4 + qh];
    const float Ov = f0 * Kbuf[0][0][qh * DH + d] + f1 * Kbuf[1][0][qh * DH + d];
    const int P = ((b * KVH + g) * QPK + qh) * NSP + s;
    Op[(size_t)P * DH + d] = Ov;
    if (d == 0) { Mp[P] = M; Sp[P] = S; }
  }
}

// Combine the NSP partials per (b, head, d).
__global__ __launch_bounds__(256, 1)
void pa_combine(const float* __restrict__ Mp, const float* __restrict__ Sp,
                const float* __restrict__ Op, float* __restrict__ out) {
  const int e  = blockIdx.x * 256 + threadIdx.x;   // b*4096 + h*128 + d
  const int d  = e & 127;
  const int h  = (e >> 7) & 31;
  const int bb = e >> 12;
  const int gg = h >> 2, qh = h & 3;
  const int P  = ((bb * KVH + gg) * QPK + qh) * NSP;
  float M = NEG;
#pragma unroll
  for (int sp = 0; sp < NSP; ++sp) M = fmaxf(M, Mp[P + sp]);
  float S = 0.f, Ov = 0.f;
#pragma unroll
  for (int sp = 0; sp < NSP; ++sp) {
    const float f = __expf(Mp[P + sp] - M);
    S  += f * Sp[P + sp];
    Ov += f * Op[(size_t)(P + sp) * DH + d];
  }
  out[e] = Ov / S;
}

extern "C" void kernel_launch(void* const* d_in, const int* in_sizes, int n_in,
                              void* d_out, int out_size, void* d_ws, size_t ws_size,
                              hipStream_t stream) {
  (void)n_in; (void)out_size; (void)ws_size;
  const float* query        = (const float*)d_in[0];
  const float* key_cache    = (const float*)d_in[1];
  const float* value_cache  = (const float*)d_in[2];
  const float* alibi_blocks = (const float*)d_in[3];
  const float* alibi_slopes = (const float*)d_in[4];
  const int*   block_list   = (const int*)d_in[5];
  const int*   block_groups = (const int*)d_in[6];
  const int*   block_usage  = (const int*)d_in[7];
  float*       out          = (float*)d_out;
  const int U = in_sizes[5];

  const int NP = BATCH * KVH * QPK * NSP;          // 8192 partials
  float* Mp = (float*)d_ws;
  float* Sp = Mp + NP;
  float* Op = Sp + NP;

  pa_partial<<<dim3(BATCH * KVH * NSP), dim3(128), 0, stream>>>(
      query, key_cache, value_cache, alibi_blocks, alibi_slopes,
      block_list, block_groups, block_usage, Mp, Sp, Op, U);

  pa_combine<<<dim3(BATCH * NH * DH / 256), dim3(256), 0, stream>>>(Mp, Sp, Op, out);
}